// Round 1
// baseline (1331.429 us; speedup 1.0000x reference)
//
#include <hip/hip_runtime.h>

// SP_DNN: two fused 1->256->256->256->256 MLPs (sin activations) + strided rowwise dot.
// fp16 MFMA (16x16x32) with fp32 accumulate; activations LDS-resident per 64-row block.

typedef _Float16 f16x8 __attribute__((ext_vector_type(8)));
typedef _Float16 f16x4 __attribute__((ext_vector_type(4)));
typedef float f32x4 __attribute__((ext_vector_type(4)));

// ---------------------------------------------------------------------------
// Prepack: 6 matrices W[k][n] (256x256 f32, k-major) -> fp16 W^T chunk-major:
// dst[L][c][n][kk] = W[c*64+kk][n], L in 0..5, c in 0..3, n in 0..255, kk in 0..63
// ---------------------------------------------------------------------------
__global__ void prepack(const float* __restrict__ xW1, const float* __restrict__ xW2,
                        const float* __restrict__ xW3, const float* __restrict__ tW1,
                        const float* __restrict__ tW2, const float* __restrict__ tW3,
                        _Float16* __restrict__ dst)
{
    int g = blockIdx.x * 256 + threadIdx.x;   // 6*65536 threads exactly
    int L = g >> 16;
    int r = g & 65535;
    int c = r >> 14;
    int n = (r >> 6) & 255;
    int kk = r & 63;
    const float* W;
    switch (L) {
        case 0: W = xW1; break;
        case 1: W = xW2; break;
        case 2: W = xW3; break;
        case 3: W = tW1; break;
        case 4: W = tW2; break;
        default: W = tW3; break;
    }
    dst[g] = (_Float16)W[(c * 64 + kk) * 256 + n];
}

// ---------------------------------------------------------------------------
// Main fused kernel. Block = 256 threads (4 waves), tile = 64 rows.
// hbuf: activations [m=64][k=256] fp16, XOR-swizzled rows (32 KB).
// wbuf: per-wave private W^T chunk [64 n][64 k] fp16, swizzled (4 x 8 KB).
// Swizzle: byte-within-128B-group XOR ((row&7)<<4) -> 2-way bank aliasing (free).
// ---------------------------------------------------------------------------

__device__ __forceinline__ void layer0_scalar(
    const float* __restrict__ x, int row0, int sel,
    const float* __restrict__ W0, const float* __restrict__ b0,
    _Float16* __restrict__ hbuf, int tid)
{
    int m = tid >> 2;        // 64 rows, 4 threads per row
    int q = tid & 3;         // each thread does 64 of the 256 channels
    float xv = x[(row0 + m) * 2 + sel];
#pragma unroll
    for (int g = 0; g < 8; ++g) {
        int n0 = q * 64 + g * 8;
        f16x8 hv;
#pragma unroll
        for (int e = 0; e < 8; ++e) {
            float z = fmaf(xv, W0[n0 + e], b0[n0 + e]);
            hv[e] = (_Float16)__sinf(z);
        }
        int nbyte = n0 * 2;                                  // multiple of 16
        int sw = (nbyte & 127) ^ ((m & 7) << 4);
        *(f16x8*)((char*)hbuf + m * 512 + (nbyte & ~127) + sw) = hv;
    }
}

// One 256->256 layer: acc[i][j] = h @ W (+bias, sin, write-back if WRITE_H).
// Weights are the MFMA A operand (rows = out-channel band of this wave),
// activations are B (cols = batch rows). D: col=lane&15=m, row=quad*4+r=n.
template<bool WRITE_H>
__device__ __forceinline__ void gemm_layer(
    const _Float16* __restrict__ Wl,     // packed layer base [4][256][64]
    const float* __restrict__ bias,      // 256 f32 (only used if WRITE_H)
    _Float16* __restrict__ hbuf,
    _Float16* __restrict__ wbw,          // this wave's 4096-elem wbuf region
    f32x4 acc[4][4],
    int lane, int ln, int quad, int wave)
{
    f32x4 zero = {0.f, 0.f, 0.f, 0.f};
#pragma unroll
    for (int i = 0; i < 4; ++i)
#pragma unroll
        for (int j = 0; j < 4; ++j)
            acc[i][j] = zero;

#pragma unroll
    for (int c = 0; c < 4; ++c) {
        // Stage this wave's 64x64 K-chunk (8 KB) into its private LDS region.
        // No barrier: only this wave reads it; DS ordering handles W-after-R.
        const f16x8* gsrc = (const f16x8*)(Wl + c * 16384 + wave * 4096);
#pragma unroll
        for (int it = 0; it < 8; ++it) {
            int u = it * 64 + lane;          // 16B unit; coalesced 1KB/instr
            int nl = u >> 3, kb = u & 7;
            f16x8 v = gsrc[u];
            int sw = (kb << 4) ^ ((nl & 7) << 4);
            *(f16x8*)((char*)wbw + nl * 128 + sw) = v;
        }
#pragma unroll
        for (int ks = 0; ks < 2; ++ks) {
            f16x8 bfr[4], afr[4];
#pragma unroll
            for (int j = 0; j < 4; ++j) {    // B: activations, all 64 rows
                int m = 16 * j + ln;
                int kbyte = c * 128 + ks * 64 + quad * 16;
                int sw = (kbyte & 127) ^ ((m & 7) << 4);
                bfr[j] = *(const f16x8*)((const char*)hbuf + m * 512 + (kbyte & ~127) + sw);
            }
#pragma unroll
            for (int i = 0; i < 4; ++i) {    // A: this wave's channel band
                int nl = 16 * i + ln;
                int kbyte = ks * 64 + quad * 16;   // < 128
                int sw = kbyte ^ ((nl & 7) << 4);
                afr[i] = *(const f16x8*)((const char*)wbw + nl * 128 + sw);
            }
#pragma unroll
            for (int i = 0; i < 4; ++i)
#pragma unroll
                for (int j = 0; j < 4; ++j)
                    acc[i][j] = __builtin_amdgcn_mfma_f32_16x16x32_f16(
                        afr[i], bfr[j], acc[i][j], 0, 0, 0);
        }
    }
    __syncthreads();   // all waves done reading hbuf for this layer
    if (WRITE_H) {
#pragma unroll
        for (int i = 0; i < 4; ++i) {
            int nb = wave * 64 + 16 * i + quad * 4;          // 4 consecutive channels
            f32x4 bv = *(const f32x4*)&bias[nb];
#pragma unroll
            for (int j = 0; j < 4; ++j) {
                int m = 16 * j + ln;
                f16x4 hv;
                hv[0] = (_Float16)__sinf(acc[i][j][0] + bv[0]);
                hv[1] = (_Float16)__sinf(acc[i][j][1] + bv[1]);
                hv[2] = (_Float16)__sinf(acc[i][j][2] + bv[2]);
                hv[3] = (_Float16)__sinf(acc[i][j][3] + bv[3]);
                int nbyte = nb * 2;                          // multiple of 8
                int sw = (nbyte & 127) ^ ((m & 7) << 4);
                *(f16x4*)((char*)hbuf + m * 512 + (nbyte & ~127) + sw) = hv;
            }
        }
        __syncthreads();   // writes visible before next layer's B reads
    }
}

__global__ __launch_bounds__(256, 2)
void mlp_fused(const float* __restrict__ x,
               const float* __restrict__ xW0, const float* __restrict__ xb0,
               const float* __restrict__ xb1, const float* __restrict__ xb2,
               const float* __restrict__ xb3,
               const float* __restrict__ tW0, const float* __restrict__ tb0,
               const float* __restrict__ tb1, const float* __restrict__ tb2,
               const float* __restrict__ tb3,
               const _Float16* __restrict__ Wp,
               float* __restrict__ out)
{
    __shared__ _Float16 hbuf[64 * 256];      // 32 KB
    __shared__ _Float16 wbuf[4 * 4096];      // 32 KB (8 KB per wave)

    const int tid = threadIdx.x;
    const int lane = tid & 63;
    const int wave = tid >> 6;
    const int ln = lane & 15;
    const int quad = lane >> 4;
    const int row0 = blockIdx.x * 64;
    _Float16* wbw = wbuf + wave * 4096;

    f32x4 xacc[4][4], tacc[4][4];

    // ----- x-MLP -----
    layer0_scalar(x, row0, 0, xW0, xb0, hbuf, tid);
    __syncthreads();
    gemm_layer<true >(Wp + 0 * 65536, xb1, hbuf, wbw, tacc, lane, ln, quad, wave);
    gemm_layer<true >(Wp + 1 * 65536, xb2, hbuf, wbw, tacc, lane, ln, quad, wave);
    gemm_layer<false>(Wp + 2 * 65536, xb1, hbuf, wbw, xacc, lane, ln, quad, wave);
    // xacc = x-MLP layer3 pre-bias output, kept in registers

    // ----- t-MLP -----
    layer0_scalar(x, row0, 1, tW0, tb0, hbuf, tid);
    __syncthreads();
    gemm_layer<true >(Wp + 3 * 65536, tb1, hbuf, wbw, tacc, lane, ln, quad, wave);
    gemm_layer<true >(Wp + 4 * 65536, tb2, hbuf, wbw, tacc, lane, ln, quad, wave);
    gemm_layer<false>(Wp + 5 * 65536, tb1, hbuf, wbw, tacc, lane, ln, quad, wave);

    // ----- combine: even/odd strided dot, fp32 -----
    float ev[4] = {0.f, 0.f, 0.f, 0.f};
    float od[4] = {0.f, 0.f, 0.f, 0.f};
#pragma unroll
    for (int i = 0; i < 4; ++i) {
        int nb = wave * 64 + 16 * i + quad * 4;
        f32x4 xb = *(const f32x4*)&xb3[nb];
        f32x4 tb = *(const f32x4*)&tb3[nb];
#pragma unroll
        for (int j = 0; j < 4; ++j) {
            float a0 = xacc[i][j][0] + xb[0], c0 = tacc[i][j][0] + tb[0];
            float a1 = xacc[i][j][1] + xb[1], c1 = tacc[i][j][1] + tb[1];
            float a2 = xacc[i][j][2] + xb[2], c2 = tacc[i][j][2] + tb[2];
            float a3 = xacc[i][j][3] + xb[3], c3 = tacc[i][j][3] + tb[3];
            ev[j] += a0 * c0 + a2 * c2;      // channel parity = reg index parity
            od[j] += a1 * c1 + a3 * c3;
        }
    }
#pragma unroll
    for (int j = 0; j < 4; ++j) {            // reduce over the 4 quads
        ev[j] += __shfl_xor(ev[j], 16, 64);
        ev[j] += __shfl_xor(ev[j], 32, 64);
        od[j] += __shfl_xor(od[j], 16, 64);
        od[j] += __shfl_xor(od[j], 32, 64);
    }

    float* red = (float*)hbuf;               // hbuf free after last gemm's sync
    if (lane < 16) {
#pragma unroll
        for (int j = 0; j < 4; ++j) {
            red[wave * 128 + j * 32 + lane * 2 + 0] = ev[j];
            red[wave * 128 + j * 32 + lane * 2 + 1] = od[j];
        }
    }
    __syncthreads();
    if (tid < 128) {                         // sum the 4 wave partials; coalesced store
        int jj = tid >> 5, m16 = (tid >> 1) & 15, p = tid & 1;
        int base = jj * 32 + m16 * 2 + p;
        float s = red[base] + red[128 + base] + red[256 + base] + red[384 + base];
        out[(row0 + 16 * jj + m16) * 2 + p] = s;
    }
}

// ---------------------------------------------------------------------------
extern "C" void kernel_launch(void* const* d_in, const int* in_sizes, int n_in,
                              void* d_out, int out_size, void* d_ws, size_t ws_size,
                              hipStream_t stream)
{
    const float* x   = (const float*)d_in[0];
    const float* xW0 = (const float*)d_in[1];
    const float* xb0 = (const float*)d_in[2];
    const float* xW1 = (const float*)d_in[3];
    const float* xb1 = (const float*)d_in[4];
    const float* xW2 = (const float*)d_in[5];
    const float* xb2 = (const float*)d_in[6];
    const float* xW3 = (const float*)d_in[7];
    const float* xb3 = (const float*)d_in[8];
    const float* tW0 = (const float*)d_in[9];
    const float* tb0 = (const float*)d_in[10];
    const float* tW1 = (const float*)d_in[11];
    const float* tb1 = (const float*)d_in[12];
    const float* tW2 = (const float*)d_in[13];
    const float* tb2 = (const float*)d_in[14];
    const float* tW3 = (const float*)d_in[15];
    const float* tb3 = (const float*)d_in[16];

    _Float16* Wp = (_Float16*)d_ws;          // 6*65536 fp16 = 768 KB
    const int N = in_sizes[0] / 2;           // 1,000,000 (divisible by 64)

    prepack<<<1536, 256, 0, stream>>>(xW1, xW2, xW3, tW1, tW2, tW3, Wp);
    mlp_fused<<<N / 64, 256, 0, stream>>>(x, xW0, xb0, xb1, xb2, xb3,
                                          tW0, tb0, tb1, tb2, tb3,
                                          Wp, (float*)d_out);
}

// Round 2
// 1133.999 us; speedup vs baseline: 1.1741x; 1.1741x over previous
//
#include <hip/hip_runtime.h>

// SP_DNN: two fused 1->256->256->256->256 MLPs (sin activations) + strided rowwise dot.
// fp16 MFMA (16x16x32), fp32 accumulate. Activations LDS-resident (64-row tile);
// weights read DIRECTLY from L2-resident packed buffer into A-fragment registers
// (no LDS staging for weights -> LDS pipe load halved vs previous round).

typedef _Float16 f16x8 __attribute__((ext_vector_type(8)));
typedef _Float16 f16x4 __attribute__((ext_vector_type(4)));
typedef float f32x4 __attribute__((ext_vector_type(4)));

#define HROW 264  // hbuf row stride in f16 elements (528 B = 33*16 B; breaks pow2 stride)

// ---------------------------------------------------------------------------
// Prepack: 6 matrices W[k][n] (256x256 f32, k-major) -> fp16 A-fragment-major:
// idx = ((((c*2+ks)*16 + nhi)*4 + quad)*16 + ln)*8 + j
//   n = nhi*16+ln, k = c*64 + ks*32 + quad*8 + j
// so a wave's A-frag group (c,ks,i) is one contiguous, lane-coalesced 1 KB block.
// ---------------------------------------------------------------------------
__global__ void prepack(const float* __restrict__ xW1, const float* __restrict__ xW2,
                        const float* __restrict__ xW3, const float* __restrict__ tW1,
                        const float* __restrict__ tW2, const float* __restrict__ tW3,
                        _Float16* __restrict__ dst)
{
    int g = blockIdx.x * 256 + threadIdx.x;   // 6*65536 threads exactly
    int L = g >> 16;
    int r = g & 65535;
    int j    = r & 7;
    int ln   = (r >> 3) & 15;
    int quad = (r >> 7) & 3;
    int nhi  = (r >> 9) & 15;
    int ks   = (r >> 13) & 1;
    int c    = (r >> 14) & 3;
    const float* W;
    switch (L) {
        case 0: W = xW1; break;
        case 1: W = xW2; break;
        case 2: W = xW3; break;
        case 3: W = tW1; break;
        case 4: W = tW2; break;
        default: W = tW3; break;
    }
    int n = nhi * 16 + ln;
    int k = c * 64 + ks * 32 + quad * 8 + j;
    dst[g] = (_Float16)W[k * 256 + n];
}

// ---------------------------------------------------------------------------
// Main fused kernel. Block = 256 threads (4 waves), tile = 64 rows.
// hbuf: activations [m=64][k=256] fp16, 528 B row stride (33 KB).
// ---------------------------------------------------------------------------

__device__ __forceinline__ void layer0_scalar(
    const float* __restrict__ x, int row0, int sel,
    const float* __restrict__ W0, const float* __restrict__ b0,
    _Float16* __restrict__ hbuf, int tid)
{
    int m = tid >> 2;        // 64 rows, 4 threads per row
    int q = tid & 3;         // each thread does 64 of the 256 channels
    float xv = x[(row0 + m) * 2 + sel];
#pragma unroll
    for (int g = 0; g < 8; ++g) {
        int n0 = q * 64 + g * 8;
        f16x8 hv;
#pragma unroll
        for (int e = 0; e < 8; ++e) {
            float z = fmaf(xv, W0[n0 + e], b0[n0 + e]);
            hv[e] = (_Float16)__sinf(z);
        }
        *(f16x8*)(hbuf + m * HROW + n0) = hv;
    }
}

// One 256->256 layer. Weights = MFMA A operand, loaded straight from global
// (L2-resident packed buffer), double-buffered over the 8 K-groups.
// Activations = B operand from hbuf. D: col=lane&15=m(row), row=quad*4+r = channel.
template<bool WRITE_H>
__device__ __forceinline__ void gemm_layer(
    const _Float16* __restrict__ Wl,     // packed layer base (65536 elems)
    const float* __restrict__ bias,      // 256 f32 (only used if WRITE_H)
    _Float16* __restrict__ hbuf,
    f32x4 acc[4][4],
    int lane, int ln, int quad, int wave)
{
    f32x4 zero = {0.f, 0.f, 0.f, 0.f};
#pragma unroll
    for (int i = 0; i < 4; ++i)
#pragma unroll
        for (int j = 0; j < 4; ++j)
            acc[i][j] = zero;

    // Per-wave A base: group g (=c*2+ks) at base + g*8192 + i*512 (+lane*8)
    const _Float16* abase = Wl + wave * 2048 + lane * 8;

    f16x8 afr[2][4];
#pragma unroll
    for (int i = 0; i < 4; ++i)
        afr[0][i] = *(const f16x8*)(abase + i * 512);

#pragma unroll
    for (int g = 0; g < 8; ++g) {
        if (g < 7) {
#pragma unroll
            for (int i = 0; i < 4; ++i)
                afr[(g + 1) & 1][i] = *(const f16x8*)(abase + (g + 1) * 8192 + i * 512);
        }
        f16x8 bfr[4];
#pragma unroll
        for (int j = 0; j < 4; ++j) {    // B: activations, all 64 rows
            int m = 16 * j + ln;
            bfr[j] = *(const f16x8*)(hbuf + m * HROW + g * 32 + quad * 8);
        }
#pragma unroll
        for (int i = 0; i < 4; ++i)
#pragma unroll
            for (int j = 0; j < 4; ++j)
                acc[i][j] = __builtin_amdgcn_mfma_f32_16x16x32_f16(
                    afr[g & 1][i], bfr[j], acc[i][j], 0, 0, 0);
    }
    __syncthreads();   // all waves done reading hbuf for this layer
    if (WRITE_H) {
#pragma unroll
        for (int i = 0; i < 4; ++i) {
            int nb = wave * 64 + 16 * i + quad * 4;          // 4 consecutive channels
            f32x4 bv = *(const f32x4*)&bias[nb];
#pragma unroll
            for (int j = 0; j < 4; ++j) {
                int m = 16 * j + ln;
                f16x4 hv;
                hv[0] = (_Float16)__sinf(acc[i][j][0] + bv[0]);
                hv[1] = (_Float16)__sinf(acc[i][j][1] + bv[1]);
                hv[2] = (_Float16)__sinf(acc[i][j][2] + bv[2]);
                hv[3] = (_Float16)__sinf(acc[i][j][3] + bv[3]);
                *(f16x4*)(hbuf + m * HROW + nb) = hv;
            }
        }
        __syncthreads();   // writes visible before next layer's B reads
    }
}

__global__ __launch_bounds__(256, 2)
void mlp_fused(const float* __restrict__ x,
               const float* __restrict__ xW0, const float* __restrict__ xb0,
               const float* __restrict__ xb1, const float* __restrict__ xb2,
               const float* __restrict__ xb3,
               const float* __restrict__ tW0, const float* __restrict__ tb0,
               const float* __restrict__ tb1, const float* __restrict__ tb2,
               const float* __restrict__ tb3,
               const _Float16* __restrict__ Wp,
               float* __restrict__ out)
{
    __shared__ __align__(16) _Float16 hbuf[64 * HROW];   // 33 KB

    const int tid = threadIdx.x;
    const int lane = tid & 63;
    const int wave = tid >> 6;
    const int ln = lane & 15;
    const int quad = lane >> 4;
    const int row0 = blockIdx.x * 64;

    f32x4 xacc[4][4], tacc[4][4];

    // ----- x-MLP -----
    layer0_scalar(x, row0, 0, xW0, xb0, hbuf, tid);
    __syncthreads();
    gemm_layer<true >(Wp + 0 * 65536, xb1, hbuf, tacc, lane, ln, quad, wave);
    gemm_layer<true >(Wp + 1 * 65536, xb2, hbuf, tacc, lane, ln, quad, wave);
    gemm_layer<false>(Wp + 2 * 65536, xb1, hbuf, xacc, lane, ln, quad, wave);
    // xacc = x-MLP layer3 pre-bias output, kept in registers

    // ----- t-MLP -----
    layer0_scalar(x, row0, 1, tW0, tb0, hbuf, tid);
    __syncthreads();
    gemm_layer<true >(Wp + 3 * 65536, tb1, hbuf, tacc, lane, ln, quad, wave);
    gemm_layer<true >(Wp + 4 * 65536, tb2, hbuf, tacc, lane, ln, quad, wave);
    gemm_layer<false>(Wp + 5 * 65536, tb1, hbuf, tacc, lane, ln, quad, wave);

    // ----- combine: even/odd strided dot, fp32 -----
    float ev[4] = {0.f, 0.f, 0.f, 0.f};
    float od[4] = {0.f, 0.f, 0.f, 0.f};
#pragma unroll
    for (int i = 0; i < 4; ++i) {
        int nb = wave * 64 + 16 * i + quad * 4;
        f32x4 xb = *(const f32x4*)&xb3[nb];
        f32x4 tb = *(const f32x4*)&tb3[nb];
#pragma unroll
        for (int j = 0; j < 4; ++j) {
            float a0 = xacc[i][j][0] + xb[0], c0 = tacc[i][j][0] + tb[0];
            float a1 = xacc[i][j][1] + xb[1], c1 = tacc[i][j][1] + tb[1];
            float a2 = xacc[i][j][2] + xb[2], c2 = tacc[i][j][2] + tb[2];
            float a3 = xacc[i][j][3] + xb[3], c3 = tacc[i][j][3] + tb[3];
            ev[j] += a0 * c0 + a2 * c2;      // channel parity = reg index parity
            od[j] += a1 * c1 + a3 * c3;
        }
    }
#pragma unroll
    for (int j = 0; j < 4; ++j) {            // reduce over the 4 quads
        ev[j] += __shfl_xor(ev[j], 16, 64);
        ev[j] += __shfl_xor(ev[j], 32, 64);
        od[j] += __shfl_xor(od[j], 16, 64);
        od[j] += __shfl_xor(od[j], 32, 64);
    }

    float* red = (float*)hbuf;               // hbuf free after last gemm's sync
    if (lane < 16) {
#pragma unroll
        for (int j = 0; j < 4; ++j) {
            red[wave * 128 + j * 32 + lane * 2 + 0] = ev[j];
            red[wave * 128 + j * 32 + lane * 2 + 1] = od[j];
        }
    }
    __syncthreads();
    if (tid < 128) {                         // sum the 4 wave partials; coalesced store
        int jj = tid >> 5, m16 = (tid >> 1) & 15, p = tid & 1;
        int base = jj * 32 + m16 * 2 + p;
        float s = red[base] + red[128 + base] + red[256 + base] + red[384 + base];
        out[(row0 + 16 * jj + m16) * 2 + p] = s;
    }
}

// ---------------------------------------------------------------------------
extern "C" void kernel_launch(void* const* d_in, const int* in_sizes, int n_in,
                              void* d_out, int out_size, void* d_ws, size_t ws_size,
                              hipStream_t stream)
{
    const float* x   = (const float*)d_in[0];
    const float* xW0 = (const float*)d_in[1];
    const float* xb0 = (const float*)d_in[2];
    const float* xW1 = (const float*)d_in[3];
    const float* xb1 = (const float*)d_in[4];
    const float* xW2 = (const float*)d_in[5];
    const float* xb2 = (const float*)d_in[6];
    const float* xW3 = (const float*)d_in[7];
    const float* xb3 = (const float*)d_in[8];
    const float* tW0 = (const float*)d_in[9];
    const float* tb0 = (const float*)d_in[10];
    const float* tW1 = (const float*)d_in[11];
    const float* tb1 = (const float*)d_in[12];
    const float* tW2 = (const float*)d_in[13];
    const float* tb2 = (const float*)d_in[14];
    const float* tW3 = (const float*)d_in[15];
    const float* tb3 = (const float*)d_in[16];

    _Float16* Wp = (_Float16*)d_ws;          // 6*65536 fp16 = 768 KB
    const int N = in_sizes[0] / 2;           // 1,000,000 (divisible by 64)

    prepack<<<1536, 256, 0, stream>>>(xW1, xW2, xW3, tW1, tW2, tW3, Wp);
    mlp_fused<<<N / 64, 256, 0, stream>>>(x, xW0, xb0, xb1, xb2, xb3,
                                          tW0, tb0, tb1, tb2, tb3,
                                          Wp, (float*)d_out);
}

// Round 3
// 1100.903 us; speedup vs baseline: 1.2094x; 1.0301x over previous
//
#include <hip/hip_runtime.h>

// SP_DNN: two fused 1->256->256->256->256 MLPs (sin activations) + strided rowwise dot.
// fp16 MFMA (16x16x32), fp32 accumulate. Activations in double-buffered LDS
// (2 x 32 KB, XOR-swizzled 16B units -> conflict-free B reads); weights read
// directly from L2-resident packed buffer into A-fragment registers.

typedef _Float16 f16x8 __attribute__((ext_vector_type(8)));
typedef _Float16 f16x4 __attribute__((ext_vector_type(4)));
typedef float f32x4 __attribute__((ext_vector_type(4)));

// Swizzled hbuf byte offset: row m (0..63, 512 B stride), kbyte in [0,512).
// 16B unit index XORed with (m&7): any 8-lane chunk of a B-read covers all
// 32 banks exactly once; writeback/layer0 patterns are <=2-way (free).
__device__ __forceinline__ int hswz(int m, int kbyte) {
    return m * 512 + ((((kbyte >> 4) ^ (m & 7)) & 31) << 4) + (kbyte & 15);
}

// ---------------------------------------------------------------------------
// Prepack: 6 matrices W[k][n] (256x256 f32, k-major) -> fp16 A-fragment-major:
// idx = ((((c*2+ks)*16 + nhi)*4 + quad)*16 + ln)*8 + j
//   n = nhi*16+ln, k = c*64 + ks*32 + quad*8 + j
// ---------------------------------------------------------------------------
__global__ void prepack(const float* __restrict__ xW1, const float* __restrict__ xW2,
                        const float* __restrict__ xW3, const float* __restrict__ tW1,
                        const float* __restrict__ tW2, const float* __restrict__ tW3,
                        _Float16* __restrict__ dst)
{
    int g = blockIdx.x * 256 + threadIdx.x;   // 6*65536 threads exactly
    int L = g >> 16;
    int r = g & 65535;
    int j    = r & 7;
    int ln   = (r >> 3) & 15;
    int quad = (r >> 7) & 3;
    int nhi  = (r >> 9) & 15;
    int ks   = (r >> 13) & 1;
    int c    = (r >> 14) & 3;
    const float* W;
    switch (L) {
        case 0: W = xW1; break;
        case 1: W = xW2; break;
        case 2: W = xW3; break;
        case 3: W = tW1; break;
        case 4: W = tW2; break;
        default: W = tW3; break;
    }
    int n = nhi * 16 + ln;
    int k = c * 64 + ks * 32 + quad * 8 + j;
    dst[g] = (_Float16)W[k * 256 + n];
}

// ---------------------------------------------------------------------------
// Main fused kernel. Block = 256 threads (4 waves), tile = 64 rows.
// ---------------------------------------------------------------------------

__device__ __forceinline__ void layer0_scalar(
    const float* __restrict__ x, int row0, int sel,
    const float* __restrict__ W0, const float* __restrict__ b0,
    _Float16* __restrict__ hb, int tid)
{
    int m = tid >> 2;        // 64 rows, 4 threads per row
    int q = tid & 3;         // each thread does 64 of the 256 channels
    float xv = x[(row0 + m) * 2 + sel];
#pragma unroll
    for (int g = 0; g < 8; ++g) {
        int n0 = q * 64 + g * 8;
        f16x8 hv;
#pragma unroll
        for (int e = 0; e < 8; ++e) {
            float z = fmaf(xv, W0[n0 + e], b0[n0 + e]);
            hv[e] = (_Float16)__sinf(z);
        }
        *(f16x8*)((char*)hb + hswz(m, n0 * 2)) = hv;
    }
}

// One 256->256 layer. Weights = MFMA A operand from global (L2-resident),
// double-buffered over the 8 K-groups. Activations = B operand from rb.
// If WRITE_H: sin(acc+bias) -> wb (the OTHER LDS buffer), then ONE barrier.
// D layout: col=lane&15 = batch row m, row=quad*4+r = out channel.
template<bool WRITE_H>
__device__ __forceinline__ void gemm_layer(
    const _Float16* __restrict__ Wl,     // packed layer base (65536 elems)
    const float* __restrict__ bias,      // 256 f32 (only used if WRITE_H)
    const _Float16* __restrict__ rb,     // read buffer (prev activations)
    _Float16* __restrict__ wb,           // write buffer (next activations)
    f32x4 acc[4][4],
    int lane, int ln, int quad, int wave)
{
    f32x4 zero = {0.f, 0.f, 0.f, 0.f};
#pragma unroll
    for (int i = 0; i < 4; ++i)
#pragma unroll
        for (int j = 0; j < 4; ++j)
            acc[i][j] = zero;

    // Per-wave A base: group g at base + g*8192 + i*512 (+lane*8)
    const _Float16* abase = Wl + wave * 2048 + lane * 8;

    f16x8 afr[2][4];
#pragma unroll
    for (int i = 0; i < 4; ++i)
        afr[0][i] = *(const f16x8*)(abase + i * 512);

#pragma unroll
    for (int g = 0; g < 8; ++g) {
        if (g < 7) {
#pragma unroll
            for (int i = 0; i < 4; ++i)
                afr[(g + 1) & 1][i] = *(const f16x8*)(abase + (g + 1) * 8192 + i * 512);
        }
        f16x8 bfr[4];
#pragma unroll
        for (int j = 0; j < 4; ++j) {    // B: activations, all 64 rows
            bfr[j] = *(const f16x8*)((const char*)rb +
                                     hswz(16 * j + ln, g * 64 + quad * 16));
        }
#pragma unroll
        for (int i = 0; i < 4; ++i)
#pragma unroll
            for (int j = 0; j < 4; ++j)
                acc[i][j] = __builtin_amdgcn_mfma_f32_16x16x32_f16(
                    afr[g & 1][i], bfr[j], acc[i][j], 0, 0, 0);
    }
    if (WRITE_H) {
#pragma unroll
        for (int i = 0; i < 4; ++i) {
            int nb = wave * 64 + 16 * i + quad * 4;          // 4 consecutive channels
            f32x4 bv = *(const f32x4*)&bias[nb];
#pragma unroll
            for (int j = 0; j < 4; ++j) {
                f16x4 hv;
                hv[0] = (_Float16)__sinf(acc[i][j][0] + bv[0]);
                hv[1] = (_Float16)__sinf(acc[i][j][1] + bv[1]);
                hv[2] = (_Float16)__sinf(acc[i][j][2] + bv[2]);
                hv[3] = (_Float16)__sinf(acc[i][j][3] + bv[3]);
                *(f16x4*)((char*)wb + hswz(16 * j + ln, nb * 2)) = hv;
            }
        }
        __syncthreads();   // writes visible before next layer's B reads
    }
}

__global__ __launch_bounds__(256, 2)
void mlp_fused(const float* __restrict__ x,
               const float* __restrict__ xW0, const float* __restrict__ xb0,
               const float* __restrict__ xb1, const float* __restrict__ xb2,
               const float* __restrict__ xb3,
               const float* __restrict__ tW0, const float* __restrict__ tb0,
               const float* __restrict__ tb1, const float* __restrict__ tb2,
               const float* __restrict__ tb3,
               const _Float16* __restrict__ Wp,
               float* __restrict__ out)
{
    __shared__ __align__(16) _Float16 hbuf[2][64 * 256];   // 2 x 32 KB

    const int tid = threadIdx.x;
    const int lane = tid & 63;
    const int wave = tid >> 6;
    const int ln = lane & 15;
    const int quad = lane >> 4;
    const int row0 = blockIdx.x * 64;

    f32x4 xacc[4][4], tacc[4][4];

    // ----- x-MLP -----  (read buf / write buf ping-pong; 1 barrier per layer)
    layer0_scalar(x, row0, 0, xW0, xb0, hbuf[0], tid);
    __syncthreads();
    gemm_layer<true >(Wp + 0 * 65536, xb1, hbuf[0], hbuf[1], tacc, lane, ln, quad, wave);
    gemm_layer<true >(Wp + 1 * 65536, xb2, hbuf[1], hbuf[0], tacc, lane, ln, quad, wave);
    gemm_layer<false>(Wp + 2 * 65536, nullptr, hbuf[0], nullptr, xacc, lane, ln, quad, wave);
    // xacc = x-MLP layer3 pre-bias output, kept in registers.

    // ----- t-MLP -----
    // buf1 is dead (its readers drained at the barrier inside gemm layer 2).
    layer0_scalar(x, row0, 1, tW0, tb0, hbuf[1], tid);
    __syncthreads();
    gemm_layer<true >(Wp + 3 * 65536, tb1, hbuf[1], hbuf[0], tacc, lane, ln, quad, wave);
    gemm_layer<true >(Wp + 4 * 65536, tb2, hbuf[0], hbuf[1], tacc, lane, ln, quad, wave);
    gemm_layer<false>(Wp + 5 * 65536, nullptr, hbuf[1], nullptr, tacc, lane, ln, quad, wave);

    // ----- combine: even/odd strided dot, fp32 -----
    float ev[4] = {0.f, 0.f, 0.f, 0.f};
    float od[4] = {0.f, 0.f, 0.f, 0.f};
#pragma unroll
    for (int i = 0; i < 4; ++i) {
        int nb = wave * 64 + 16 * i + quad * 4;
        f32x4 xb = *(const f32x4*)&xb3[nb];
        f32x4 tb = *(const f32x4*)&tb3[nb];
#pragma unroll
        for (int j = 0; j < 4; ++j) {
            float a0 = xacc[i][j][0] + xb[0], c0 = tacc[i][j][0] + tb[0];
            float a1 = xacc[i][j][1] + xb[1], c1 = tacc[i][j][1] + tb[1];
            float a2 = xacc[i][j][2] + xb[2], c2 = tacc[i][j][2] + tb[2];
            float a3 = xacc[i][j][3] + xb[3], c3 = tacc[i][j][3] + tb[3];
            ev[j] += a0 * c0 + a2 * c2;      // channel parity = reg index parity
            od[j] += a1 * c1 + a3 * c3;
        }
    }
#pragma unroll
    for (int j = 0; j < 4; ++j) {            // reduce over the 4 quads
        ev[j] += __shfl_xor(ev[j], 16, 64);
        ev[j] += __shfl_xor(ev[j], 32, 64);
        od[j] += __shfl_xor(od[j], 16, 64);
        od[j] += __shfl_xor(od[j], 32, 64);
    }

    float* red = (float*)hbuf[0];            // buf0 dead here (tg3 read buf1)
    if (lane < 16) {
#pragma unroll
        for (int j = 0; j < 4; ++j) {
            red[wave * 128 + j * 32 + lane * 2 + 0] = ev[j];
            red[wave * 128 + j * 32 + lane * 2 + 1] = od[j];
        }
    }
    __syncthreads();
    if (tid < 128) {                         // sum the 4 wave partials; coalesced store
        int jj = tid >> 5, m16 = (tid >> 1) & 15, p = tid & 1;
        int base = jj * 32 + m16 * 2 + p;
        float s = red[base] + red[128 + base] + red[256 + base] + red[384 + base];
        out[(row0 + 16 * jj + m16) * 2 + p] = s;
    }
}

// ---------------------------------------------------------------------------
extern "C" void kernel_launch(void* const* d_in, const int* in_sizes, int n_in,
                              void* d_out, int out_size, void* d_ws, size_t ws_size,
                              hipStream_t stream)
{
    const float* x   = (const float*)d_in[0];
    const float* xW0 = (const float*)d_in[1];
    const float* xb0 = (const float*)d_in[2];
    const float* xW1 = (const float*)d_in[3];
    const float* xb1 = (const float*)d_in[4];
    const float* xW2 = (const float*)d_in[5];
    const float* xb2 = (const float*)d_in[6];
    const float* xW3 = (const float*)d_in[7];
    const float* xb3 = (const float*)d_in[8];
    const float* tW0 = (const float*)d_in[9];
    const float* tb0 = (const float*)d_in[10];
    const float* tW1 = (const float*)d_in[11];
    const float* tb1 = (const float*)d_in[12];
    const float* tW2 = (const float*)d_in[13];
    const float* tb2 = (const float*)d_in[14];
    const float* tW3 = (const float*)d_in[15];
    const float* tb3 = (const float*)d_in[16];

    _Float16* Wp = (_Float16*)d_ws;          // 6*65536 fp16 = 768 KB
    const int N = in_sizes[0] / 2;           // 1,000,000 (divisible by 64)

    prepack<<<1536, 256, 0, stream>>>(xW1, xW2, xW3, tW1, tW2, tW3, Wp);
    mlp_fused<<<N / 64, 256, 0, stream>>>(x, xW0, xb0, xb1, xb2, xb3,
                                          tW0, tb0, tb1, tb2, tb3,
                                          Wp, (float*)d_out);
}